// Round 14
// baseline (661.527 us; speedup 1.0000x reference)
//
#include <hip/hip_runtime.h>

#define BB   4
#define CC   256
#define NPIX 4096
#define AST2 40    // mfma-core LDS row stride (shorts), 80 B, 16B-aligned
#define YST  72    // (unused by new pv; kept for reference)

typedef __attribute__((ext_vector_type(8)))  short bf16x8;
typedef __attribute__((ext_vector_type(8)))  _Float16 f16x8;
typedef __attribute__((ext_vector_type(4)))  short short4v;
typedef __attribute__((ext_vector_type(16))) float f32x16;

__device__ __forceinline__ short f2h(float f) {
    _Float16 h = (_Float16)f;           // v_cvt_f16_f32 (RNE)
    return __builtin_bit_cast(short, h);
}
__device__ __forceinline__ int cdrow(int r, int l5) {
    return (r & 3) + 8 * (r >> 2) + 4 * l5;   // verified m74/m101 C/D row map
}
// S fixed-point codec: s in (-128,128), scale 256 -> |err| <= 2^-9
__device__ __forceinline__ short s_enc(float v) {
    float c = fmaxf(fminf(v, 127.9f), -127.9f);
    return (short)__float2int_rn(c * 256.0f);
}
__device__ __forceinline__ float s_dec(short v) {
    return (float)v * (1.0f / 256.0f);
}

// ---------------------------------------------------------------------------
// Single-fp16 MFMA core: 128x128 tile, K=256, register-prefetch pipelined.
// 20 KB LDS. (R6-proven; used by proj & out)
// ---------------------------------------------------------------------------
__device__ __forceinline__ void mfma_core_f16(
    const short* __restrict__ A, const short* __restrict__ B, f32x16 acc[2][2])
{
    __shared__ short LA[128 * AST2], LB[128 * AST2];
    const int t = threadIdx.x;
    const int lane = t & 63, w = t >> 6;
    const int l31 = lane & 31, l5 = lane >> 5;
    const int nq = (w & 1) * 64, mq = (w >> 1) * 64;
    const int sr = t >> 1;
    const int sk = (t & 1) * 16;
    const size_t gs = (size_t)sr * 256 + sk;
    const int ls = sr * AST2 + sk;

    bf16x8 rA0 = *(const bf16x8*)(A + gs);
    bf16x8 rA1 = *(const bf16x8*)(A + gs + 8);
    bf16x8 rB0 = *(const bf16x8*)(B + gs);
    bf16x8 rB1 = *(const bf16x8*)(B + gs + 8);

    for (int k0 = 0; k0 < 256; k0 += 32) {
        __syncthreads();
        *(bf16x8*)&LA[ls]     = rA0;
        *(bf16x8*)&LA[ls + 8] = rA1;
        *(bf16x8*)&LB[ls]     = rB0;
        *(bf16x8*)&LB[ls + 8] = rB1;
        __syncthreads();
        if (k0 + 32 < 256) {
            size_t g = gs + k0 + 32;
            rA0 = *(const bf16x8*)(A + g);
            rA1 = *(const bf16x8*)(A + g + 8);
            rB0 = *(const bf16x8*)(B + g);
            rB1 = *(const bf16x8*)(B + g + 8);
        }
#pragma unroll
        for (int ks = 0; ks < 2; ks++) {
            f16x8 a[2], b[2];
#pragma unroll
            for (int s = 0; s < 2; s++) {
                a[s] = *(const f16x8*)&LA[(nq + s * 32 + l31) * AST2 + ks * 16 + l5 * 8];
                b[s] = *(const f16x8*)&LB[(mq + s * 32 + l31) * AST2 + ks * 16 + l5 * 8];
            }
#pragma unroll
            for (int s = 0; s < 2; s++)
#pragma unroll
                for (int u = 0; u < 2; u++)
                    acc[s][u] = __builtin_amdgcn_mfma_f32_32x32x16_f16(a[s], b[u], acc[s][u], 0, 0, 0);
        }
    }
}

// ---------------- pack kernels ----------------

// all 5 weights fp32 -> fp16, same layout. grid (64, 5)
__global__ __launch_bounds__(256) void pack_w5(
    const float* __restrict__ w0, const float* __restrict__ w1,
    const float* __restrict__ w2, const float* __restrict__ w3,
    const float* __restrict__ w4, short* __restrict__ wall)
{
    int which = blockIdx.y;
    const float* w = which == 0 ? w0 : which == 1 ? w1 : which == 2 ? w2
                   : which == 3 ? w3 : w4;
    int idx = blockIdx.x * 1024 + threadIdx.x * 4;
    float4 v = *(const float4*)(w + idx);
    short4v h;
    h.x = f2h(v.x); h.y = f2h(v.y); h.z = f2h(v.z); h.w = f2h(v.w);
    *(short4v*)(wall + which * 65536 + idx) = h;
}

// transpose fp32 [c][n] -> single fp16 [n][c]. grid (128,8,4)
__global__ __launch_bounds__(256) void pack_t_f16(
    const float* __restrict__ in, short* __restrict__ o16)
{
    __shared__ short T[32][36];
    const int b  = blockIdx.z;
    const int n0 = blockIdx.x * 32;
    const int c0 = blockIdx.y * 32;
    const float* src = in + (size_t)b * CC * NPIX;
    const int t = threadIdx.x;
    const int r = t >> 3, q = t & 7;
    float4 v = *(const float4*)(src + (size_t)(c0 + r) * NPIX + n0 + q * 4);
    T[q * 4 + 0][r] = f2h(v.x);
    T[q * 4 + 1][r] = f2h(v.y);
    T[q * 4 + 2][r] = f2h(v.z);
    T[q * 4 + 3][r] = f2h(v.w);
    __syncthreads();
    short4v o;
    o.x = T[r][q * 4 + 0];
    o.y = T[r][q * 4 + 1];
    o.z = T[r][q * 4 + 2];
    o.w = T[r][q * 4 + 3];
    size_t oo = (size_t)b * CC * NPIX + (size_t)(n0 + r) * 256 + c0 + q * 4;
    *(short4v*)(o16 + oo) = o;
}

// transpose fp16 [256][4096] -> fp16 [4096][256]. grid (128,8,4)
__global__ __launch_bounds__(256) void tr16_cn(
    const short* __restrict__ in, short* __restrict__ outp)
{
    __shared__ short T[32][33];
    const int b  = blockIdx.z;
    const int n0 = blockIdx.x * 32;
    const int c0 = blockIdx.y * 32;
    const short* src = in + (size_t)b * CC * NPIX;
    short* dst = outp + (size_t)b * CC * NPIX;
    const int t = threadIdx.x;
    const int r = t >> 3, q = t & 7;
    short4v v = *(const short4v*)(src + (size_t)(c0 + r) * NPIX + n0 + q * 4);
    T[q * 4 + 0][r] = v.x;
    T[q * 4 + 1][r] = v.y;
    T[q * 4 + 2][r] = v.z;
    T[q * 4 + 3][r] = v.w;
    __syncthreads();
    short4v o;
    o.x = T[r][q * 4 + 0];
    o.y = T[r][q * 4 + 1];
    o.z = T[r][q * 4 + 2];
    o.w = T[r][q * 4 + 3];
    *(short4v*)(dst + (size_t)(n0 + r) * 256 + c0 + q * 4) = o;
}

// Vt[c][m] = x3f.flat[m*256+c] (already fp16). grid (128,8,4)
__global__ __launch_bounds__(256) void packVt_bf(
    const short* __restrict__ x3f, short* __restrict__ Vt)
{
    __shared__ short T[32][33];
    const int b  = blockIdx.z;
    const int m0 = blockIdx.x * 32;
    const int c0 = blockIdx.y * 32;
    const short* in = x3f + (size_t)b * CC * NPIX;
    short* out = Vt + (size_t)b * CC * NPIX;
    const int t = threadIdx.x;
    const int r = t >> 3, q = t & 7;
    short4v v = *(const short4v*)(in + (size_t)(m0 + r) * CC + c0 + q * 4);
    T[q * 4 + 0][r] = v.x;
    T[q * 4 + 1][r] = v.y;
    T[q * 4 + 2][r] = v.z;
    T[q * 4 + 3][r] = v.w;
    __syncthreads();
    short4v o;
    o.x = T[r][q * 4 + 0];
    o.y = T[r][q * 4 + 1];
    o.z = T[r][q * 4 + 2];
    o.w = T[r][q * 4 + 3];
    *(short4v*)(out + (size_t)(c0 + r) * NPIX + m0 + q * 4) = o;
}

// ---------------- GEMM kernels ----------------

// proj. grid (32, 2, 12). p=0 -> x1, p=1 -> x2, p=2 -> x3; all fp16 [c][n].
__global__ __launch_bounds__(256) void proj_mfma(
    const short* __restrict__ wpf, const short* __restrict__ xtf,
    const float* __restrict__ b_teta, const float* __restrict__ b_fi,
    const float* __restrict__ b_gi,
    short* __restrict__ x1f, short* __restrict__ x2f, short* __restrict__ x3f)
{
    const int z = blockIdx.z, p = z >> 2, b = z & 3;
    const int n0 = blockIdx.x * 128, c0 = blockIdx.y * 128;
    const size_t CN = (size_t)CC * NPIX;
    const short* Ah = wpf + p * 65536 + c0 * 256;
    const short* Bh = xtf + (size_t)b * CN + (size_t)n0 * 256;
    const float* bias = p == 0 ? b_teta : p == 1 ? b_fi : b_gi;
    short* dst = p == 0 ? x1f : p == 1 ? x2f : x3f;

    f32x16 acc[2][2] = {};
    mfma_core_f16(Ah, Bh, acc);

    const int t = threadIdx.x, lane = t & 63, w = t >> 6;
    const int l31 = lane & 31, l5 = lane >> 5;
    const int aq = (w & 1) * 64, bq = (w >> 1) * 64;
#pragma unroll
    for (int s = 0; s < 2; s++)
#pragma unroll
        for (int u = 0; u < 2; u++)
#pragma unroll
            for (int r = 0; r < 16; r++) {
                int c = c0 + aq + s * 32 + cdrow(r, l5);
                int n = n0 + bq + u * 32 + l31;
                float v = acc[s][u][r] + bias[c];
                size_t o = (size_t)b * CN + (size_t)c * NPIX + n;
                dst[o] = f2h(v);
            }
}

// scores: 256n x 128m tile, K=256. S int16 fixed-point + col partial stats.
// grid (32 mT, 16 nT) = 512 blocks (2/CU resident, zero tail).
// Wave w: n-half h=w&1 (128 rows), m-half g=w>>1 (64 cols); acc[4][2].
__global__ __launch_bounds__(256, 2) void scores_mfma(
    const short* __restrict__ x1f, const short* __restrict__ x2tf,
    short* __restrict__ S16, float* __restrict__ pm, float* __restrict__ pl)
{
    __shared__ short LA[256 * AST2];   // 20 KB
    __shared__ short LB[128 * AST2];   // 10 KB
    const int m0 = blockIdx.x * 128, n0 = blockIdx.y * 256;
    const short* A = x1f + (size_t)n0 * 256;
    const short* B = x2tf + (size_t)m0 * 256;

    const int t = threadIdx.x, lane = t & 63, w = t >> 6;
    const int l31 = lane & 31, l5 = lane >> 5;
    const int h = w & 1, g = w >> 1;

    // staging: A row t (32 shorts/step), B row t>>1 half (t&1)
    const size_t gsA = (size_t)t * 256;
    const int lsA = t * AST2;
    const int srB = t >> 1, skB = (t & 1) * 16;
    const size_t gsB = (size_t)srB * 256 + skB;
    const int lsB = srB * AST2 + skB;

    bf16x8 rA0 = *(const bf16x8*)(A + gsA);
    bf16x8 rA1 = *(const bf16x8*)(A + gsA + 8);
    bf16x8 rA2 = *(const bf16x8*)(A + gsA + 16);
    bf16x8 rA3 = *(const bf16x8*)(A + gsA + 24);
    bf16x8 rB0 = *(const bf16x8*)(B + gsB);
    bf16x8 rB1 = *(const bf16x8*)(B + gsB + 8);

    f32x16 acc[4][2] = {};

    for (int k0 = 0; k0 < 256; k0 += 32) {
        __syncthreads();
        *(bf16x8*)&LA[lsA]      = rA0;
        *(bf16x8*)&LA[lsA + 8]  = rA1;
        *(bf16x8*)&LA[lsA + 16] = rA2;
        *(bf16x8*)&LA[lsA + 24] = rA3;
        *(bf16x8*)&LB[lsB]      = rB0;
        *(bf16x8*)&LB[lsB + 8]  = rB1;
        __syncthreads();
        if (k0 + 32 < 256) {
            size_t gA = gsA + k0 + 32;
            size_t gB = gsB + k0 + 32;
            rA0 = *(const bf16x8*)(A + gA);
            rA1 = *(const bf16x8*)(A + gA + 8);
            rA2 = *(const bf16x8*)(A + gA + 16);
            rA3 = *(const bf16x8*)(A + gA + 24);
            rB0 = *(const bf16x8*)(B + gB);
            rB1 = *(const bf16x8*)(B + gB + 8);
        }
#pragma unroll
        for (int ks = 0; ks < 2; ks++) {
            f16x8 a[4], b[2];
#pragma unroll
            for (int s = 0; s < 4; s++)
                a[s] = *(const f16x8*)&LA[(h * 128 + s * 32 + l31) * AST2 + ks * 16 + l5 * 8];
#pragma unroll
            for (int u = 0; u < 2; u++)
                b[u] = *(const f16x8*)&LB[(g * 64 + u * 32 + l31) * AST2 + ks * 16 + l5 * 8];
#pragma unroll
            for (int s = 0; s < 4; s++)
#pragma unroll
                for (int u = 0; u < 2; u++)
                    acc[s][u] = __builtin_amdgcn_mfma_f32_32x32x16_f16(a[s], b[u], acc[s][u], 0, 0, 0);
        }
    }

    // C-write (int16 fixed-point)
#pragma unroll
    for (int s = 0; s < 4; s++)
#pragma unroll
        for (int u = 0; u < 2; u++)
#pragma unroll
            for (int r = 0; r < 16; r++) {
                int n = n0 + h * 128 + s * 32 + cdrow(r, l5);
                int m = m0 + g * 64 + u * 32 + l31;
                S16[(size_t)n * NPIX + m] = s_enc(acc[s][u][r]);
            }

    // column partial stats over this wave's 128-row half (group = 2*nT + h).
#pragma unroll
    for (int u = 0; u < 2; u++) {
        float vmax = -1e30f;
#pragma unroll
        for (int s = 0; s < 4; s++)
#pragma unroll
            for (int r = 0; r < 16; r++) vmax = fmaxf(vmax, acc[s][u][r]);
        float vsum = 0.0f;
#pragma unroll
        for (int s = 0; s < 4; s++)
#pragma unroll
            for (int r = 0; r < 16; r++) vsum += __expf(acc[s][u][r] - vmax);
        // combine with partner lane (lane^32) holding the other 16 rows/stripe
        float vmax2 = __shfl_xor(vmax, 32, 64);
        float vsum2 = __shfl_xor(vsum, 32, 64);
        float mc = fmaxf(vmax, vmax2);
        float sc = vsum * __expf(vmax - mc) + vsum2 * __expf(vmax2 - mc);
        if (l5 == 0) {
            size_t pidx = (size_t)(blockIdx.y * 2 + h) * NPIX + m0 + g * 64 + u * 32 + l31;
            pm[pidx] = mc;
            pl[pidx] = sc;
        }
    }
}

// out: relu(x + bias + W.(sum_q Ypq)^T), single batch. grid (32, 4).
// B operand = sum of 4 fp16 K-quarter partials, combined during staging.
__global__ __launch_bounds__(256) void out_mfma(
    const short* __restrict__ wof,
    const float* __restrict__ b_o1, const float* __restrict__ b_o2,
    const short* __restrict__ Yp,
    const float* __restrict__ x, float* __restrict__ out, int b)
{
    __shared__ short LA[128 * AST2], LB[128 * AST2];
    const size_t CN_ = (size_t)NPIX * CC;
    const int ch0 = blockIdx.y * 128;
    const int pix0 = blockIdx.x * 128;
    const int mode = ch0 < 256 ? 0 : 1;
    const short* W = wof + mode * 65536 + (size_t)(ch0 & 255) * 256;
    const short* Yq = Yp + (size_t)mode * 4 * CN_;
    const float* bias = mode == 0 ? b_o1 : b_o2;

    const int t = threadIdx.x, lane = t & 63, w = t >> 6;
    const int l31 = lane & 31, l5 = lane >> 5;
    const int nq = (w & 1) * 64, mq = (w >> 1) * 64;
    const int sr = t >> 1;
    const int sk = (t & 1) * 16;
    const size_t gsA = (size_t)sr * 256 + sk;
    const size_t gsB = (size_t)(pix0 + sr) * 256 + sk;
    const int ls = sr * AST2 + sk;

    f32x16 acc[2][2] = {};

    bf16x8 rA0 = *(const bf16x8*)(W + gsA);
    bf16x8 rA1 = *(const bf16x8*)(W + gsA + 8);
    f16x8 rB0, rB1;
    {
        rB0 = *(const f16x8*)(Yq + gsB);
        rB1 = *(const f16x8*)(Yq + gsB + 8);
#pragma unroll
        for (int q = 1; q < 4; q++) {
            rB0 = rB0 + *(const f16x8*)(Yq + (size_t)q * CN_ + gsB);
            rB1 = rB1 + *(const f16x8*)(Yq + (size_t)q * CN_ + gsB + 8);
        }
    }

    for (int k0 = 0; k0 < 256; k0 += 32) {
        __syncthreads();
        *(bf16x8*)&LA[ls]    = rA0;
        *(bf16x8*)&LA[ls + 8] = rA1;
        *(f16x8*)&LB[ls]     = rB0;
        *(f16x8*)&LB[ls + 8] = rB1;
        __syncthreads();
        if (k0 + 32 < 256) {
            size_t gA = gsA + k0 + 32;
            size_t gB = gsB + k0 + 32;
            rA0 = *(const bf16x8*)(W + gA);
            rA1 = *(const bf16x8*)(W + gA + 8);
            rB0 = *(const f16x8*)(Yq + gB);
            rB1 = *(const f16x8*)(Yq + gB + 8);
#pragma unroll
            for (int q = 1; q < 4; q++) {
                rB0 = rB0 + *(const f16x8*)(Yq + (size_t)q * CN_ + gB);
                rB1 = rB1 + *(const f16x8*)(Yq + (size_t)q * CN_ + gB + 8);
            }
        }
#pragma unroll
        for (int ks = 0; ks < 2; ks++) {
            f16x8 a[2], bb[2];
#pragma unroll
            for (int s = 0; s < 2; s++) {
                a[s]  = *(const f16x8*)&LA[(nq + s * 32 + l31) * AST2 + ks * 16 + l5 * 8];
                bb[s] = *(const f16x8*)&LB[(mq + s * 32 + l31) * AST2 + ks * 16 + l5 * 8];
            }
#pragma unroll
            for (int s = 0; s < 2; s++)
#pragma unroll
                for (int u = 0; u < 2; u++)
                    acc[s][u] = __builtin_amdgcn_mfma_f32_32x32x16_f16(a[s], bb[u], acc[s][u], 0, 0, 0);
        }
    }

    const int aq = (w & 1) * 64, bq = (w >> 1) * 64;
#pragma unroll
    for (int s = 0; s < 2; s++)
#pragma unroll
        for (int u = 0; u < 2; u++)
#pragma unroll
            for (int r = 0; r < 16; r++) {
                int ch = ch0 + aq + s * 32 + cdrow(r, l5);
                int pix = pix0 + bq + u * 32 + l31;
                int chm = ch & 255;
                float v = acc[s][u][r] + bias[chm] +
                          x[((size_t)b * CC + chm) * NPIX + pix];
                out[((size_t)b * 2 * CC + ch) * NPIX + pix] = fmaxf(v, 0.0f);
            }
}

// stats: blocks [0,64) combine 32 col partials -> cm/cli;
//        blocks [64,4160) reduce one S16 row -> rm/rli.
__global__ __launch_bounds__(256) void stats16_kernel(
    const short* __restrict__ S16,
    const float* __restrict__ pm, const float* __restrict__ pl,
    float* __restrict__ cm, float* __restrict__ cli,
    float* __restrict__ rm, float* __restrict__ rli)
{
    __shared__ float sm[4][64], sl[4][64];
    __shared__ float red[4];
    const int t = threadIdx.x;
    if (blockIdx.x < 64) {
        const int cl = t & 63, ch = t >> 6;
        const int col = blockIdx.x * 64 + cl;
        float m = -1e30f, l = 0.0f;
        for (int i = ch * 8; i < ch * 8 + 8; i++) {
            float m2 = pm[(size_t)i * NPIX + col];
            float l2 = pl[(size_t)i * NPIX + col];
            float mn = fmaxf(m, m2);
            l = l * __expf(m - mn) + l2 * __expf(m2 - mn);
            m = mn;
        }
        sm[ch][cl] = m;
        sl[ch][cl] = l;
        __syncthreads();
        if (ch == 0) {
#pragma unroll
            for (int j = 1; j < 4; j++) {
                float m2 = sm[j][cl], l2 = sl[j][cl];
                float mn = fmaxf(m, m2);
                l = l * __expf(m - mn) + l2 * __expf(m2 - mn);
                m = mn;
            }
            cm[col]  = m;
            cli[col] = 1.0f / l;
        }
    } else {
        const int row = blockIdx.x - 64;
        const short* sp = S16 + (size_t)row * NPIX;
        const int w = t >> 6, lane = t & 63;
        float s4[16];
#pragma unroll
        for (int i = 0; i < 4; i++) {
            short4v v = *(const short4v*)(sp + (i * 256 + t) * 4);
            s4[i * 4 + 0] = s_dec(v.x);
            s4[i * 4 + 1] = s_dec(v.y);
            s4[i * 4 + 2] = s_dec(v.z);
            s4[i * 4 + 3] = s_dec(v.w);
        }
        float m = -1e30f;
#pragma unroll
        for (int i = 0; i < 16; i++) m = fmaxf(m, s4[i]);
        for (int off = 32; off; off >>= 1) m = fmaxf(m, __shfl_xor(m, off, 64));
        if (lane == 0) red[w] = m;
        __syncthreads();
        m = fmaxf(fmaxf(red[0], red[1]), fmaxf(red[2], red[3]));
        __syncthreads();
        float sum = 0.0f;
#pragma unroll
        for (int i = 0; i < 16; i++) sum += __expf(s4[i] - m);
        for (int off = 32; off; off >>= 1) sum += __shfl_xor(sum, off, 64);
        if (lane == 0) red[w] = sum;
        __syncthreads();
        if (t == 0) {
            rm[row]  = m;
            rli[row] = 1.0f / (red[0] + red[1] + red[2] + red[3]);
        }
    }
}

// ---------------- pv: barrier-free, LDS-free, fragment-direct ----------------
// grid (64 nT, 4 kq, 2 mode) = 512 blocks. Block: 64n x 256c over K=1024.
// Each lane loads its MFMA fragments DIRECTLY from global in fragment layout:
//   A-frag: P[row = n0+nst+l31][k = kk + l5*8 .. +8], computed in-register
//           from S16 (exp + row/col stats).
//   B-frag: Vt[c = cb+u*32+l31][k ...], L2/L3-hot (128-way block reuse).
// No __syncthreads, no LDS -> high occupancy, free wave pipelining.
__global__ __launch_bounds__(256) void pv_kernel(
    const short* __restrict__ S16, const short* __restrict__ Vt,
    const float* __restrict__ rmv, const float* __restrict__ rliv,
    const float* __restrict__ cmv, const float* __restrict__ cliv,
    short* __restrict__ Yp)
{
    const int mode = blockIdx.z, kq = blockIdx.y;
    const int n0 = blockIdx.x * 64;
    const int kbase = kq * 1024;

    const int t = threadIdx.x, lane = t & 63, w = t >> 6;
    const int l31 = lane & 31, l5 = lane >> 5;
    const int nst = (w & 1) * 32, cb = (w >> 1) * 128;

    const int arow = n0 + nst + l31;
    const float mrow = rmv[arow];
    const float lrow = rliv[arow];
    const short* sp = S16 + (size_t)arow * NPIX + kbase + l5 * 8;
    const short* vb0 = Vt + (size_t)(cb + l31) * NPIX + kbase + l5 * 8;
    const short* vb1 = vb0 + (size_t)32 * NPIX;
    const short* vb2 = vb0 + (size_t)64 * NPIX;
    const short* vb3 = vb0 + (size_t)96 * NPIX;
    const float* cmp = cmv + kbase + l5 * 8;
    const float* clp = cliv + kbase + l5 * 8;

    f32x16 acc[4] = {};
    for (int it = 0; it < 64; it++) {
        const int kk = it * 16;
        short4v s0 = *(const short4v*)(sp + kk);
        short4v s1 = *(const short4v*)(sp + kk + 4);
        float d[8];
        d[0] = s_dec(s0.x); d[1] = s_dec(s0.y);
        d[2] = s_dec(s0.z); d[3] = s_dec(s0.w);
        d[4] = s_dec(s1.x); d[5] = s_dec(s1.y);
        d[6] = s_dec(s1.z); d[7] = s_dec(s1.w);
        f16x8 af;
        if (mode == 0) {
#pragma unroll
            for (int j = 0; j < 8; j++)
                af[j] = (_Float16)(__expf(d[j] - mrow) * lrow);
        } else {
            float4 cm0 = *(const float4*)(cmp + kk);
            float4 cm1 = *(const float4*)(cmp + kk + 4);
            float4 cl0 = *(const float4*)(clp + kk);
            float4 cl1 = *(const float4*)(clp + kk + 4);
            af[0] = (_Float16)(__expf(d[0] - cm0.x) * cl0.x);
            af[1] = (_Float16)(__expf(d[1] - cm0.y) * cl0.y);
            af[2] = (_Float16)(__expf(d[2] - cm0.z) * cl0.z);
            af[3] = (_Float16)(__expf(d[3] - cm0.w) * cl0.w);
            af[4] = (_Float16)(__expf(d[4] - cm1.x) * cl1.x);
            af[5] = (_Float16)(__expf(d[5] - cm1.y) * cl1.y);
            af[6] = (_Float16)(__expf(d[6] - cm1.z) * cl1.z);
            af[7] = (_Float16)(__expf(d[7] - cm1.w) * cl1.w);
        }
        f16x8 bf0 = *(const f16x8*)(vb0 + kk);
        f16x8 bf1 = *(const f16x8*)(vb1 + kk);
        f16x8 bf2 = *(const f16x8*)(vb2 + kk);
        f16x8 bf3 = *(const f16x8*)(vb3 + kk);
        acc[0] = __builtin_amdgcn_mfma_f32_32x32x16_f16(af, bf0, acc[0], 0, 0, 0);
        acc[1] = __builtin_amdgcn_mfma_f32_32x32x16_f16(af, bf1, acc[1], 0, 0, 0);
        acc[2] = __builtin_amdgcn_mfma_f32_32x32x16_f16(af, bf2, acc[2], 0, 0, 0);
        acc[3] = __builtin_amdgcn_mfma_f32_32x32x16_f16(af, bf3, acc[3], 0, 0, 0);
    }

    short* Yo = Yp + (size_t)(mode * 4 + kq) * ((size_t)NPIX * CC);
#pragma unroll
    for (int u = 0; u < 4; u++)
#pragma unroll
        for (int r = 0; r < 16; r++) {
            int rr = cdrow(r, l5);
            Yo[(size_t)(n0 + nst + rr) * CC + cb + u * 32 + l31] = f2h(acc[u][r]);
        }
}

extern "C" void kernel_launch(void* const* d_in, const int* in_sizes, int n_in,
                              void* d_out, int out_size, void* d_ws, size_t ws_size,
                              hipStream_t stream)
{
    (void)in_sizes; (void)n_in; (void)out_size; (void)ws_size;
    const float* x      = (const float*)d_in[0];
    const float* w_teta = (const float*)d_in[1];
    const float* b_teta = (const float*)d_in[2];
    const float* w_fi   = (const float*)d_in[3];
    const float* b_fi   = (const float*)d_in[4];
    const float* w_gi   = (const float*)d_in[5];
    const float* b_gi   = (const float*)d_in[6];
    const float* w_o1   = (const float*)d_in[7];
    const float* b_o1   = (const float*)d_in[8];
    const float* w_o2   = (const float*)d_in[9];
    const float* b_o2   = (const float*)d_in[10];
    float* out = (float*)d_out;

    const size_t CN = (size_t)CC * NPIX;       // 1M elements
    const size_t NN = (size_t)NPIX * NPIX;     // 16.7M
    short* wsp   = (short*)d_ws;
    // --- persistent regions ---
    short* S16   = wsp;                         // 32 MB (int16 scores)
    short* Yp    = S16 + NN;                    // 16 MB (8 x 2 MB fp16)
    short* x1f   = Yp + 16 * CN;                // 8 MB (fp16)
    short* x2tf  = x1f + BB * CN;               // 8 MB (fp16)
    short* Vtb   = x2tf + BB * CN;              // 8 MB (fp16)
    float* cm    = (float*)(Vtb + BB * CN);
    float* cli   = cm + NPIX;
    float* rm    = cli + NPIX;
    float* rli   = rm + NPIX;
    float* pm    = rli + NPIX;                  // 64*NPIX = 1 MB (32 used)
    float* pl    = pm + 64 * NPIX;              // 1 MB
    short* wall  = (short*)(pl + 64 * NPIX);    // 5*65536 fp16 weights
    short* wpf   = wall;                        // teta, fi, gi
    short* wof   = wall + 3 * 65536;            // o1, o2
    // --- aliases (pre-phase only; dead before batch loop) ---
    short* xtf  = Yp;                           // 8 MB in Yp region
    short* x2f  = S16;                          // 8 MB in S16 region
    short* x3f  = S16 + BB * CN;                // 8 MB in S16 region

    dim3 blk(256);
    pack_w5<<<dim3(64, 5), blk, 0, stream>>>(w_teta, w_fi, w_gi, w_o1, w_o2, wall);
    pack_t_f16<<<dim3(128, 8, 4), blk, 0, stream>>>(x, xtf);

    proj_mfma<<<dim3(32, 2, 12), blk, 0, stream>>>(
        wpf, xtf, b_teta, b_fi, b_gi, x1f, x2f, x3f);

    tr16_cn<<<dim3(128, 8, 4), blk, 0, stream>>>(x2f, x2tf);
    packVt_bf<<<dim3(128, 8, 4), blk, 0, stream>>>(x3f, Vtb);

    for (int b = 0; b < BB; b++) {
        scores_mfma<<<dim3(32, 16), blk, 0, stream>>>(
            x1f + b * CN, x2tf + b * CN, S16, pm, pl);
        stats16_kernel<<<dim3(64 + NPIX), blk, 0, stream>>>(
            S16, pm, pl, cm, cli, rm, rli);
        pv_kernel<<<dim3(64, 4, 2), blk, 0, stream>>>(
            S16, Vtb + b * CN, rm, rli, cm, cli, Yp);
        out_mfma<<<dim3(32, 4), blk, 0, stream>>>(
            wof, b_o1, b_o2, Yp, x, out, b);
    }
}

// Round 15
// 403.312 us; speedup vs baseline: 1.6402x; 1.6402x over previous
//
#include <hip/hip_runtime.h>

#define BB   4
#define CC   256
#define NPIX 4096
#define AST2 40    // mfma-core LDS row stride (shorts), 80 B, 16B-aligned
#define YST  72    // pv LDS row stride (shorts), 144 B, 16B-aligned

typedef __attribute__((ext_vector_type(8)))  short bf16x8;
typedef __attribute__((ext_vector_type(8)))  _Float16 f16x8;
typedef __attribute__((ext_vector_type(4)))  short short4v;
typedef __attribute__((ext_vector_type(16))) float f32x16;

__device__ __forceinline__ short f2h(float f) {
    _Float16 h = (_Float16)f;           // v_cvt_f16_f32 (RNE)
    return __builtin_bit_cast(short, h);
}
__device__ __forceinline__ int cdrow(int r, int l5) {
    return (r & 3) + 8 * (r >> 2) + 4 * l5;   // verified m74/m101 C/D row map
}
// S fixed-point codec: s in (-128,128), scale 256 -> |err| <= 2^-9
__device__ __forceinline__ short s_enc(float v) {
    float c = fmaxf(fminf(v, 127.9f), -127.9f);
    return (short)__float2int_rn(c * 256.0f);
}
__device__ __forceinline__ float s_dec(short v) {
    return (float)v * (1.0f / 256.0f);
}

// ---------------------------------------------------------------------------
// Single-fp16 MFMA core: 128x128 tile, K=256, register-prefetch pipelined.
// 20 KB LDS. (R6-proven; used by proj)
// ---------------------------------------------------------------------------
__device__ __forceinline__ void mfma_core_f16(
    const short* __restrict__ A, const short* __restrict__ B, f32x16 acc[2][2])
{
    __shared__ short LA[128 * AST2], LB[128 * AST2];
    const int t = threadIdx.x;
    const int lane = t & 63, w = t >> 6;
    const int l31 = lane & 31, l5 = lane >> 5;
    const int nq = (w & 1) * 64, mq = (w >> 1) * 64;
    const int sr = t >> 1;
    const int sk = (t & 1) * 16;
    const size_t gs = (size_t)sr * 256 + sk;
    const int ls = sr * AST2 + sk;

    bf16x8 rA0 = *(const bf16x8*)(A + gs);
    bf16x8 rA1 = *(const bf16x8*)(A + gs + 8);
    bf16x8 rB0 = *(const bf16x8*)(B + gs);
    bf16x8 rB1 = *(const bf16x8*)(B + gs + 8);

    for (int k0 = 0; k0 < 256; k0 += 32) {
        __syncthreads();
        *(bf16x8*)&LA[ls]     = rA0;
        *(bf16x8*)&LA[ls + 8] = rA1;
        *(bf16x8*)&LB[ls]     = rB0;
        *(bf16x8*)&LB[ls + 8] = rB1;
        __syncthreads();
        if (k0 + 32 < 256) {
            size_t g = gs + k0 + 32;
            rA0 = *(const bf16x8*)(A + g);
            rA1 = *(const bf16x8*)(A + g + 8);
            rB0 = *(const bf16x8*)(B + g);
            rB1 = *(const bf16x8*)(B + g + 8);
        }
#pragma unroll
        for (int ks = 0; ks < 2; ks++) {
            f16x8 a[2], b[2];
#pragma unroll
            for (int s = 0; s < 2; s++) {
                a[s] = *(const f16x8*)&LA[(nq + s * 32 + l31) * AST2 + ks * 16 + l5 * 8];
                b[s] = *(const f16x8*)&LB[(mq + s * 32 + l31) * AST2 + ks * 16 + l5 * 8];
            }
#pragma unroll
            for (int s = 0; s < 2; s++)
#pragma unroll
                for (int u = 0; u < 2; u++)
                    acc[s][u] = __builtin_amdgcn_mfma_f32_32x32x16_f16(a[s], b[u], acc[s][u], 0, 0, 0);
        }
    }
}

// ---------------- pack kernels ----------------

// all 5 weights fp32 -> fp16, same layout. grid (64, 5)
__global__ __launch_bounds__(256) void pack_w5(
    const float* __restrict__ w0, const float* __restrict__ w1,
    const float* __restrict__ w2, const float* __restrict__ w3,
    const float* __restrict__ w4, short* __restrict__ wall)
{
    int which = blockIdx.y;
    const float* w = which == 0 ? w0 : which == 1 ? w1 : which == 2 ? w2
                   : which == 3 ? w3 : w4;
    int idx = blockIdx.x * 1024 + threadIdx.x * 4;
    float4 v = *(const float4*)(w + idx);
    short4v h;
    h.x = f2h(v.x); h.y = f2h(v.y); h.z = f2h(v.z); h.w = f2h(v.w);
    *(short4v*)(wall + which * 65536 + idx) = h;
}

// transpose fp32 [c][n] -> single fp16 [n][c]. grid (128,8,4)
__global__ __launch_bounds__(256) void pack_t_f16(
    const float* __restrict__ in, short* __restrict__ o16)
{
    __shared__ short T[32][36];
    const int b  = blockIdx.z;
    const int n0 = blockIdx.x * 32;
    const int c0 = blockIdx.y * 32;
    const float* src = in + (size_t)b * CC * NPIX;
    const int t = threadIdx.x;
    const int r = t >> 3, q = t & 7;
    float4 v = *(const float4*)(src + (size_t)(c0 + r) * NPIX + n0 + q * 4);
    T[q * 4 + 0][r] = f2h(v.x);
    T[q * 4 + 1][r] = f2h(v.y);
    T[q * 4 + 2][r] = f2h(v.z);
    T[q * 4 + 3][r] = f2h(v.w);
    __syncthreads();
    short4v o;
    o.x = T[r][q * 4 + 0];
    o.y = T[r][q * 4 + 1];
    o.z = T[r][q * 4 + 2];
    o.w = T[r][q * 4 + 3];
    size_t oo = (size_t)b * CC * NPIX + (size_t)(n0 + r) * 256 + c0 + q * 4;
    *(short4v*)(o16 + oo) = o;
}

// transpose fp16 [256][4096] -> fp16 [4096][256]. grid (128,8,4)
__global__ __launch_bounds__(256) void tr16_cn(
    const short* __restrict__ in, short* __restrict__ outp)
{
    __shared__ short T[32][33];
    const int b  = blockIdx.z;
    const int n0 = blockIdx.x * 32;
    const int c0 = blockIdx.y * 32;
    const short* src = in + (size_t)b * CC * NPIX;
    short* dst = outp + (size_t)b * CC * NPIX;
    const int t = threadIdx.x;
    const int r = t >> 3, q = t & 7;
    short4v v = *(const short4v*)(src + (size_t)(c0 + r) * NPIX + n0 + q * 4);
    T[q * 4 + 0][r] = v.x;
    T[q * 4 + 1][r] = v.y;
    T[q * 4 + 2][r] = v.z;
    T[q * 4 + 3][r] = v.w;
    __syncthreads();
    short4v o;
    o.x = T[r][q * 4 + 0];
    o.y = T[r][q * 4 + 1];
    o.z = T[r][q * 4 + 2];
    o.w = T[r][q * 4 + 3];
    *(short4v*)(dst + (size_t)(n0 + r) * 256 + c0 + q * 4) = o;
}

// Vt[c][m] = x3f.flat[m*256+c] (already fp16). grid (128,8,4)
__global__ __launch_bounds__(256) void packVt_bf(
    const short* __restrict__ x3f, short* __restrict__ Vt)
{
    __shared__ short T[32][33];
    const int b  = blockIdx.z;
    const int m0 = blockIdx.x * 32;
    const int c0 = blockIdx.y * 32;
    const short* in = x3f + (size_t)b * CC * NPIX;
    short* out = Vt + (size_t)b * CC * NPIX;
    const int t = threadIdx.x;
    const int r = t >> 3, q = t & 7;
    short4v v = *(const short4v*)(in + (size_t)(m0 + r) * CC + c0 + q * 4);
    T[q * 4 + 0][r] = v.x;
    T[q * 4 + 1][r] = v.y;
    T[q * 4 + 2][r] = v.z;
    T[q * 4 + 3][r] = v.w;
    __syncthreads();
    short4v o;
    o.x = T[r][q * 4 + 0];
    o.y = T[r][q * 4 + 1];
    o.z = T[r][q * 4 + 2];
    o.w = T[r][q * 4 + 3];
    *(short4v*)(out + (size_t)(c0 + r) * NPIX + m0 + q * 4) = o;
}

// ---------------- GEMM kernels ----------------

// proj. grid (32, 2, 12). p=0 -> x1, p=1 -> x2, p=2 -> x3; all fp16 [c][n].
__global__ __launch_bounds__(256) void proj_mfma(
    const short* __restrict__ wpf, const short* __restrict__ xtf,
    const float* __restrict__ b_teta, const float* __restrict__ b_fi,
    const float* __restrict__ b_gi,
    short* __restrict__ x1f, short* __restrict__ x2f, short* __restrict__ x3f)
{
    const int z = blockIdx.z, p = z >> 2, b = z & 3;
    const int n0 = blockIdx.x * 128, c0 = blockIdx.y * 128;
    const size_t CN = (size_t)CC * NPIX;
    const short* Ah = wpf + p * 65536 + c0 * 256;
    const short* Bh = xtf + (size_t)b * CN + (size_t)n0 * 256;
    const float* bias = p == 0 ? b_teta : p == 1 ? b_fi : b_gi;
    short* dst = p == 0 ? x1f : p == 1 ? x2f : x3f;

    f32x16 acc[2][2] = {};
    mfma_core_f16(Ah, Bh, acc);

    const int t = threadIdx.x, lane = t & 63, w = t >> 6;
    const int l31 = lane & 31, l5 = lane >> 5;
    const int aq = (w & 1) * 64, bq = (w >> 1) * 64;
#pragma unroll
    for (int s = 0; s < 2; s++)
#pragma unroll
        for (int u = 0; u < 2; u++)
#pragma unroll
            for (int r = 0; r < 16; r++) {
                int c = c0 + aq + s * 32 + cdrow(r, l5);
                int n = n0 + bq + u * 32 + l31;
                float v = acc[s][u][r] + bias[c];
                size_t o = (size_t)b * CN + (size_t)c * NPIX + n;
                dst[o] = f2h(v);
            }
}

// scores: 256n x 128m tile, K=256. S int16 fixed-point + col partial stats.
// grid (32 mT, 16 nT) = 512 blocks (2/CU resident, zero tail).
// Wave w: n-half h=w&1 (128 rows), m-half g=w>>1 (64 cols); acc[4][2].
__global__ __launch_bounds__(256, 2) void scores_mfma(
    const short* __restrict__ x1f, const short* __restrict__ x2tf,
    short* __restrict__ S16, float* __restrict__ pm, float* __restrict__ pl)
{
    __shared__ short LA[256 * AST2];   // 20 KB
    __shared__ short LB[128 * AST2];   // 10 KB
    const int m0 = blockIdx.x * 128, n0 = blockIdx.y * 256;
    const short* A = x1f + (size_t)n0 * 256;
    const short* B = x2tf + (size_t)m0 * 256;

    const int t = threadIdx.x, lane = t & 63, w = t >> 6;
    const int l31 = lane & 31, l5 = lane >> 5;
    const int h = w & 1, g = w >> 1;

    // staging: A row t (32 shorts/step), B row t>>1 half (t&1)
    const size_t gsA = (size_t)t * 256;
    const int lsA = t * AST2;
    const int srB = t >> 1, skB = (t & 1) * 16;
    const size_t gsB = (size_t)srB * 256 + skB;
    const int lsB = srB * AST2 + skB;

    bf16x8 rA0 = *(const bf16x8*)(A + gsA);
    bf16x8 rA1 = *(const bf16x8*)(A + gsA + 8);
    bf16x8 rA2 = *(const bf16x8*)(A + gsA + 16);
    bf16x8 rA3 = *(const bf16x8*)(A + gsA + 24);
    bf16x8 rB0 = *(const bf16x8*)(B + gsB);
    bf16x8 rB1 = *(const bf16x8*)(B + gsB + 8);

    f32x16 acc[4][2] = {};

    for (int k0 = 0; k0 < 256; k0 += 32) {
        __syncthreads();
        *(bf16x8*)&LA[lsA]      = rA0;
        *(bf16x8*)&LA[lsA + 8]  = rA1;
        *(bf16x8*)&LA[lsA + 16] = rA2;
        *(bf16x8*)&LA[lsA + 24] = rA3;
        *(bf16x8*)&LB[lsB]      = rB0;
        *(bf16x8*)&LB[lsB + 8]  = rB1;
        __syncthreads();
        if (k0 + 32 < 256) {
            size_t gA = gsA + k0 + 32;
            size_t gB = gsB + k0 + 32;
            rA0 = *(const bf16x8*)(A + gA);
            rA1 = *(const bf16x8*)(A + gA + 8);
            rA2 = *(const bf16x8*)(A + gA + 16);
            rA3 = *(const bf16x8*)(A + gA + 24);
            rB0 = *(const bf16x8*)(B + gB);
            rB1 = *(const bf16x8*)(B + gB + 8);
        }
#pragma unroll
        for (int ks = 0; ks < 2; ks++) {
            f16x8 a[4], b[2];
#pragma unroll
            for (int s = 0; s < 4; s++)
                a[s] = *(const f16x8*)&LA[(h * 128 + s * 32 + l31) * AST2 + ks * 16 + l5 * 8];
#pragma unroll
            for (int u = 0; u < 2; u++)
                b[u] = *(const f16x8*)&LB[(g * 64 + u * 32 + l31) * AST2 + ks * 16 + l5 * 8];
#pragma unroll
            for (int s = 0; s < 4; s++)
#pragma unroll
                for (int u = 0; u < 2; u++)
                    acc[s][u] = __builtin_amdgcn_mfma_f32_32x32x16_f16(a[s], b[u], acc[s][u], 0, 0, 0);
        }
    }

    // C-write (int16 fixed-point)
#pragma unroll
    for (int s = 0; s < 4; s++)
#pragma unroll
        for (int u = 0; u < 2; u++)
#pragma unroll
            for (int r = 0; r < 16; r++) {
                int n = n0 + h * 128 + s * 32 + cdrow(r, l5);
                int m = m0 + g * 64 + u * 32 + l31;
                S16[(size_t)n * NPIX + m] = s_enc(acc[s][u][r]);
            }

    // column partial stats over this wave's 128-row half (group = 2*nT + h).
#pragma unroll
    for (int u = 0; u < 2; u++) {
        float vmax = -1e30f;
#pragma unroll
        for (int s = 0; s < 4; s++)
#pragma unroll
            for (int r = 0; r < 16; r++) vmax = fmaxf(vmax, acc[s][u][r]);
        float vsum = 0.0f;
#pragma unroll
        for (int s = 0; s < 4; s++)
#pragma unroll
            for (int r = 0; r < 16; r++) vsum += __expf(acc[s][u][r] - vmax);
        // combine with partner lane (lane^32) holding the other 16 rows/stripe
        float vmax2 = __shfl_xor(vmax, 32, 64);
        float vsum2 = __shfl_xor(vsum, 32, 64);
        float mc = fmaxf(vmax, vmax2);
        float sc = vsum * __expf(vmax - mc) + vsum2 * __expf(vmax2 - mc);
        if (l5 == 0) {
            size_t pidx = (size_t)(blockIdx.y * 2 + h) * NPIX + m0 + g * 64 + u * 32 + l31;
            pm[pidx] = mc;
            pl[pidx] = sc;
        }
    }
}

// out: relu(x + bias + W.(sum_q Ypq)^T), single batch. 64ch x 64pix tile.
// grid (64 pixT, 8 chT) = 512 blocks (2/CU). Wave w: s=(w&1) ch-frag,
// u=(w>>1) pix-frag; acc[1]. B operand = sum of 4 fp16 K-quarter partials.
__global__ __launch_bounds__(256) void out_mfma(
    const short* __restrict__ wof,
    const float* __restrict__ b_o1, const float* __restrict__ b_o2,
    const short* __restrict__ Yp,
    const float* __restrict__ x, float* __restrict__ out, int b)
{
    __shared__ short LA[64 * AST2], LB[64 * AST2];   // 5 KB + 5 KB
    const size_t CN_ = (size_t)NPIX * CC;
    const int ch0 = blockIdx.y * 64;
    const int pix0 = blockIdx.x * 64;
    const int mode = ch0 < 256 ? 0 : 1;
    const short* W = wof + mode * 65536 + (size_t)(ch0 & 255) * 256;
    const short* Yq = Yp + (size_t)mode * 4 * CN_;
    const float* bias = mode == 0 ? b_o1 : b_o2;

    const int t = threadIdx.x, lane = t & 63, w = t >> 6;
    const int l31 = lane & 31, l5 = lane >> 5;
    const int aq = (w & 1) * 32, bq = (w >> 1) * 32;
    const int sr = t >> 2;            // staging row 0..63
    const int sk = (t & 3) * 8;       // staging k offset (8 shorts = 16 B)
    const size_t gsA = (size_t)sr * 256 + sk;
    const size_t gsB = (size_t)(pix0 + sr) * 256 + sk;
    const int ls = sr * AST2 + sk;

    f32x16 acc = {};

    bf16x8 rA0 = *(const bf16x8*)(W + gsA);
    f16x8 rB0;
    {
        rB0 = *(const f16x8*)(Yq + gsB);
#pragma unroll
        for (int q = 1; q < 4; q++)
            rB0 = rB0 + *(const f16x8*)(Yq + (size_t)q * CN_ + gsB);
    }

    for (int k0 = 0; k0 < 256; k0 += 32) {
        __syncthreads();
        *(bf16x8*)&LA[ls] = rA0;
        *(f16x8*)&LB[ls]  = rB0;
        __syncthreads();
        if (k0 + 32 < 256) {
            size_t gA = gsA + k0 + 32;
            size_t gB = gsB + k0 + 32;
            rA0 = *(const bf16x8*)(W + gA);
            rB0 = *(const f16x8*)(Yq + gB);
#pragma unroll
            for (int q = 1; q < 4; q++)
                rB0 = rB0 + *(const f16x8*)(Yq + (size_t)q * CN_ + gB);
        }
#pragma unroll
        for (int ks = 0; ks < 2; ks++) {
            f16x8 a = *(const f16x8*)&LA[(aq + l31) * AST2 + ks * 16 + l5 * 8];
            f16x8 bb = *(const f16x8*)&LB[(bq + l31) * AST2 + ks * 16 + l5 * 8];
            acc = __builtin_amdgcn_mfma_f32_32x32x16_f16(a, bb, acc, 0, 0, 0);
        }
    }

#pragma unroll
    for (int r = 0; r < 16; r++) {
        int ch = ch0 + aq + cdrow(r, l5);
        int pix = pix0 + bq + l31;
        int chm = ch & 255;
        float v = acc[r] + bias[chm] +
                  x[((size_t)b * CC + chm) * NPIX + pix];
        out[((size_t)b * 2 * CC + ch) * NPIX + pix] = fmaxf(v, 0.0f);
    }
}

// stats: blocks [0,64) combine 32 col partials -> cm/cli;
//        blocks [64,4160) reduce one S16 row -> rm/rli.
__global__ __launch_bounds__(256) void stats16_kernel(
    const short* __restrict__ S16,
    const float* __restrict__ pm, const float* __restrict__ pl,
    float* __restrict__ cm, float* __restrict__ cli,
    float* __restrict__ rm, float* __restrict__ rli)
{
    __shared__ float sm[4][64], sl[4][64];
    __shared__ float red[4];
    const int t = threadIdx.x;
    if (blockIdx.x < 64) {
        const int cl = t & 63, ch = t >> 6;
        const int col = blockIdx.x * 64 + cl;
        float m = -1e30f, l = 0.0f;
        for (int i = ch * 8; i < ch * 8 + 8; i++) {
            float m2 = pm[(size_t)i * NPIX + col];
            float l2 = pl[(size_t)i * NPIX + col];
            float mn = fmaxf(m, m2);
            l = l * __expf(m - mn) + l2 * __expf(m2 - mn);
            m = mn;
        }
        sm[ch][cl] = m;
        sl[ch][cl] = l;
        __syncthreads();
        if (ch == 0) {
#pragma unroll
            for (int j = 1; j < 4; j++) {
                float m2 = sm[j][cl], l2 = sl[j][cl];
                float mn = fmaxf(m, m2);
                l = l * __expf(m - mn) + l2 * __expf(m2 - mn);
                m = mn;
            }
            cm[col]  = m;
            cli[col] = 1.0f / l;
        }
    } else {
        const int row = blockIdx.x - 64;
        const short* sp = S16 + (size_t)row * NPIX;
        const int w = t >> 6, lane = t & 63;
        float s4[16];
#pragma unroll
        for (int i = 0; i < 4; i++) {
            short4v v = *(const short4v*)(sp + (i * 256 + t) * 4);
            s4[i * 4 + 0] = s_dec(v.x);
            s4[i * 4 + 1] = s_dec(v.y);
            s4[i * 4 + 2] = s_dec(v.z);
            s4[i * 4 + 3] = s_dec(v.w);
        }
        float m = -1e30f;
#pragma unroll
        for (int i = 0; i < 16; i++) m = fmaxf(m, s4[i]);
        for (int off = 32; off; off >>= 1) m = fmaxf(m, __shfl_xor(m, off, 64));
        if (lane == 0) red[w] = m;
        __syncthreads();
        m = fmaxf(fmaxf(red[0], red[1]), fmaxf(red[2], red[3]));
        __syncthreads();
        float sum = 0.0f;
#pragma unroll
        for (int i = 0; i < 16; i++) sum += __expf(s4[i] - m);
        for (int off = 32; off; off >>= 1) sum += __shfl_xor(sum, off, 64);
        if (lane == 0) red[w] = sum;
        __syncthreads();
        if (t == 0) {
            rm[row]  = m;
            rli[row] = 1.0f / (red[0] + red[1] + red[2] + red[3]);
        }
    }
}

// compute fp16 P fragment from int16 S fragment (both-mode helper)
__device__ __forceinline__ void compute_ph(
    const short4v sv[4], int mode, int mg,
    const float* __restrict__ cmv, const float* __restrict__ cliv,
    float mrow, float lrow, short4v ph[4])
{
    if (mode == 0) {
#pragma unroll
        for (int i = 0; i < 4; i++) {
            ph[i].x = f2h(__expf(s_dec(sv[i].x) - mrow) * lrow);
            ph[i].y = f2h(__expf(s_dec(sv[i].y) - mrow) * lrow);
            ph[i].z = f2h(__expf(s_dec(sv[i].z) - mrow) * lrow);
            ph[i].w = f2h(__expf(s_dec(sv[i].w) - mrow) * lrow);
        }
    } else {
#pragma unroll
        for (int i = 0; i < 4; i++) {
            float4 cm4 = *(const float4*)(cmv + mg + i * 4);
            float4 cl4 = *(const float4*)(cliv + mg + i * 4);
            ph[i].x = f2h(__expf(s_dec(sv[i].x) - cm4.x) * cl4.x);
            ph[i].y = f2h(__expf(s_dec(sv[i].y) - cm4.y) * cl4.y);
            ph[i].z = f2h(__expf(s_dec(sv[i].z) - cm4.z) * cl4.z);
            ph[i].w = f2h(__expf(s_dec(sv[i].w) - cm4.w) * cl4.w);
        }
    }
}

// ---------------- pv: on-the-fly P from int16 S, Yp = P @ Vt^T --------------
// grid (64 nT, 4 kq, 2 mode) = 512 blocks (2/CU). 2-deep prefetch ring.
__global__ __launch_bounds__(256) void pv_kernel(
    const short* __restrict__ S16, const short* __restrict__ Vt,
    const float* __restrict__ rmv, const float* __restrict__ rliv,
    const float* __restrict__ cmv, const float* __restrict__ cliv,
    short* __restrict__ Yp)
{
    __shared__ short LA[64 * YST];     //  9216 B
    __shared__ short LB[256 * YST];    // 36864 B
    const int mode = blockIdx.z, kq = blockIdx.y;
    const int n0 = blockIdx.x * 64;
    const int kbase = kq * 1024;

    const int t = threadIdx.x, lane = t & 63, w = t >> 6;
    const int l31 = lane & 31, l5 = lane >> 5;
    const int nst = (w & 1) * 32, cb = (w >> 1) * 128;
    const int ar = t >> 2;            // staging row 0..63
    const int ak = (t & 3) * 16;      // staging k offset (16 m values)

    const float mrow = rmv[n0 + ar];
    const float lrow = rliv[n0 + ar];
    const short* sp = S16 + (size_t)(n0 + ar) * NPIX + kbase + ak;

    // 2-deep prefetch ring: A buffers feed even steps, B buffers odd steps.
    short4v svA[4], svB[4];
    bf16x8 pbA[8], pbB[8];
#pragma unroll
    for (int i = 0; i < 4; i++) {
        svA[i] = *(const short4v*)(sp + i * 4);
        svB[i] = *(const short4v*)(sp + 64 + i * 4);
    }
#pragma unroll
    for (int i = 0; i < 4; i++) {
        const short* bp0 = Vt + (size_t)(i * 64 + ar) * NPIX + kbase + ak;
        pbA[2 * i]     = *(const bf16x8*)bp0;
        pbA[2 * i + 1] = *(const bf16x8*)(bp0 + 8);
        pbB[2 * i]     = *(const bf16x8*)(bp0 + 64);
        pbB[2 * i + 1] = *(const bf16x8*)(bp0 + 72);
    }

    f32x16 acc[4] = {};
    for (int sx = 0; sx < 8; sx++) {
        const int s = sx * 2;
        // ---------- even step s (A buffers) ----------
        {
            short4v ph[4];
            compute_ph(svA, mode, kbase + s * 64 + ak, cmv, cliv, mrow, lrow, ph);
            __syncthreads();
#pragma unroll
            for (int i = 0; i < 4; i++)
                *(short4v*)&LA[ar * YST + ak + i * 4] = ph[i];
#pragma unroll
            for (int i = 0; i < 4; i++) {
                *(bf16x8*)&LB[(i * 64 + ar) * YST + ak]     = pbA[2 * i];
                *(bf16x8*)&LB[(i * 64 + ar) * YST + ak + 8] = pbA[2 * i + 1];
            }
            __syncthreads();
            if (s + 2 < 16) {
                const short* spn = sp + (s + 2) * 64;
#pragma unroll
                for (int i = 0; i < 4; i++)
                    svA[i] = *(const short4v*)(spn + i * 4);
                int kg = kbase + (s + 2) * 64 + ak;
#pragma unroll
                for (int i = 0; i < 4; i++) {
                    const short* bp = Vt + (size_t)(i * 64 + ar) * NPIX + kg;
                    pbA[2 * i]     = *(const bf16x8*)bp;
                    pbA[2 * i + 1] = *(const bf16x8*)(bp + 8);
                }
            }
#pragma unroll
            for (int kc = 0; kc < 4; kc++) {
                f16x8 af = *(const f16x8*)&LA[(nst + l31) * YST + kc * 16 + l5 * 8];
#pragma unroll
                for (int u = 0; u < 4; u++) {
                    f16x8 bf = *(const f16x8*)&LB[(cb + u * 32 + l31) * YST + kc * 16 + l5 * 8];
                    acc[u] = __builtin_amdgcn_mfma_f32_32x32x16_f16(af, bf, acc[u], 0, 0, 0);
                }
            }
        }
        // ---------- odd step s+1 (B buffers) ----------
        {
            short4v ph[4];
            compute_ph(svB, mode, kbase + (s + 1) * 64 + ak, cmv, cliv, mrow, lrow, ph);
            __syncthreads();
#pragma unroll
            for (int i = 0; i < 4; i++)
                *(short4v*)&LA[ar * YST + ak + i * 4] = ph[i];
#pragma unroll
            for (int i = 0; i < 4; i++) {
                *(bf16x8*)&LB[(i * 64 + ar) * YST + ak]     = pbB[2 * i];
                *(bf16x8*)&LB[(i * 64 + ar) * YST + ak + 8] = pbB[2 * i + 1];
            }
            __syncthreads();
            if (s + 3 < 16) {
                const short* spn = sp + (s + 3) * 64;
#pragma unroll
                for (int i = 0; i < 4; i++)
                    svB[i] = *(const short4v*)(spn + i * 4);
                int kg = kbase + (s + 3) * 64 + ak;
#pragma unroll
                for (int i = 0; i < 4; i++) {
                    const short* bp = Vt + (size_t)(i * 64 + ar) * NPIX + kg;
                    pbB[2 * i]     = *(const bf16x8*)bp;
                    pbB[2 * i + 1] = *(const bf16x8*)(bp + 8);
                }
            }
#pragma unroll
            for (int kc = 0; kc < 4; kc++) {
                f16x8 af = *(const f16x8*)&LA[(nst + l31) * YST + kc * 16 + l5 * 8];
#pragma unroll
                for (int u = 0; u < 4; u++) {
                    f16x8 bf = *(const f16x8*)&LB[(cb + u * 32 + l31) * YST + kc * 16 + l5 * 8];
                    acc[u] = __builtin_amdgcn_mfma_f32_32x32x16_f16(af, bf, acc[u], 0, 0, 0);
                }
            }
        }
    }

    short* Yo = Yp + (size_t)(mode * 4 + kq) * ((size_t)NPIX * CC);
#pragma unroll
    for (int u = 0; u < 4; u++)
#pragma unroll
        for (int r = 0; r < 16; r++) {
            int rr = cdrow(r, l5);
            Yo[(size_t)(n0 + nst + rr) * CC + cb + u * 32 + l31] = f2h(acc[u][r]);
        }
}

extern "C" void kernel_launch(void* const* d_in, const int* in_sizes, int n_in,
                              void* d_out, int out_size, void* d_ws, size_t ws_size,
                              hipStream_t stream)
{
    (void)in_sizes; (void)n_in; (void)out_size; (void)ws_size;
    const float* x      = (const float*)d_in[0];
    const float* w_teta = (const float*)d_in[1];
    const float* b_teta = (const float*)d_in[2];
    const float* w_fi   = (const float*)d_in[3];
    const float* b_fi   = (const float*)d_in[4];
    const float* w_gi   = (const float*)d_in[5];
    const float* b_gi   = (const float*)d_in[6];
    const float* w_o1   = (const float*)d_in[7];
    const float* b_o1   = (const float*)d_in[8];
    const float* w_o2   = (const float*)d_in[9];
    const float* b_o2   = (const float*)d_in[10];
    float* out = (float*)d_out;

    const size_t CN = (size_t)CC * NPIX;       // 1M elements
    const size_t NN = (size_t)NPIX * NPIX;     // 16.7M
    short* wsp   = (short*)d_ws;
    // --- persistent regions ---
    short* S16   = wsp;                         // 32 MB (int16 scores)
    short* Yp    = S16 + NN;                    // 16 MB (8 x 2 MB fp16)
    short* x1f   = Yp + 16 * CN;                // 8 MB (fp16)
    short* x2tf  = x1f + BB * CN;               // 8 MB (fp16)
    short* Vtb   = x2tf + BB * CN;              // 8 MB (fp16)
    float* cm    = (float*)(Vtb + BB * CN);
    float* cli   = cm + NPIX;
    float* rm    = cli + NPIX;
    float* rli   = rm + NPIX;
    float* pm    = rli + NPIX;                  // 64*NPIX = 1 MB (32 used)
    float* pl    = pm + 64 * NPIX;              // 1 MB
    short* wall  = (short*)(pl + 64 * NPIX);    // 5*65536 fp16 weights
    short* wpf   = wall;                        // teta, fi, gi
    short* wof   = wall + 3 * 65536;            // o1, o2
    // --- aliases (pre-phase only; dead before batch loop) ---
    short* xtf  = Yp;                           // 8 MB in Yp region
    short* x2f  = S16;                          // 8 MB in S16 region
    short* x3f  = S16 + BB * CN;                // 8 MB in S16 region

    dim3 blk(256);
    pack_w5<<<dim3(64, 5), blk, 0, stream>>>(w_teta, w_fi, w_gi, w_o1, w_o2, wall);
    pack_t_f16<<<dim3(128, 8, 4), blk, 0, stream>>>(x, xtf);

    proj_mfma<<<dim3(32, 2, 12), blk, 0, stream>>>(
        wpf, xtf, b_teta, b_fi, b_gi, x1f, x2f, x3f);

    tr16_cn<<<dim3(128, 8, 4), blk, 0, stream>>>(x2f, x2tf);
    packVt_bf<<<dim3(128, 8, 4), blk, 0, stream>>>(x3f, Vtb);

    for (int b = 0; b < BB; b++) {
        scores_mfma<<<dim3(32, 16), blk, 0, stream>>>(
            x1f + b * CN, x2tf + b * CN, S16, pm, pl);
        stats16_kernel<<<dim3(64 + NPIX), blk, 0, stream>>>(
            S16, pm, pl, cm, cli, rm, rli);
        pv_kernel<<<dim3(64, 4, 2), blk, 0, stream>>>(
            S16, Vtb + b * CN, rm, rli, cm, cli, Yp);
        out_mfma<<<dim3(64, 8), blk, 0, stream>>>(
            wof, b_o1, b_o2, Yp, x, out, b);
    }
}